// Round 4
// baseline (226.062 us; speedup 1.0000x reference)
//
#include <hip/hip_runtime.h>

typedef unsigned short ushort_t;

#define M_DIM 1024   // 2*512 rows of x
#define N_DIM 4096   // OUT_F
#define K_DIM 4096   // IN_F
#define NFREQ 10000
constexpr float SCALE = 150.0f / 64.0f;   // 150 / sqrt(4096)

typedef __bf16 bf16x8_t __attribute__((ext_vector_type(8)));
typedef float  f32x4_t  __attribute__((ext_vector_type(4)));

__device__ inline ushort_t f2bf(float f) {
  union { float f; unsigned u; } v; v.f = f;
  unsigned r = v.u + 0x7fffu + ((v.u >> 16) & 1u);   // RNE
  return (ushort_t)(r >> 16);
}

// ---------------------------------------------------------------------------
// Kernel 1: W' = bf16( weight + s * iwht(scatter(spectrum, indices)) ), plus
// x fp32->bf16 folded in as extra grid-y slice.
// Entry-outer evaluation: each entry read ONCE per thread, signs for 16
// contiguous rows come from a Walsh LUT bit pattern (4 VALU per entry-row).
// ---------------------------------------------------------------------------
__global__ __launch_bounds__(256) void build_w4(
    const float* __restrict__ weight,
    const float* __restrict__ spectrum,
    const int* __restrict__ idx,          // [2][NFREQ]: row 0 = r (out), row 1 = c (in)
    const float* __restrict__ x,
    ushort_t* __restrict__ wb,
    ushort_t* __restrict__ xb) {
  // ---- folded cvt_x slice ----
  if (blockIdx.y == 16) {
    int flat = blockIdx.x * 256 + threadIdx.x;    // 16384 threads
#pragma unroll 4
    for (int k = 0; k < 64; ++k) {
      int i = flat + k * 16384;                   // M*K/4 = 1048576 float4s
      float4 v = ((const float4*)x)[i];
      ushort4 o;
      o.x = f2bf(v.x); o.y = f2bf(v.y); o.z = f2bf(v.z); o.w = f2bf(v.w);
      ((ushort4*)xb)[i] = o;
    }
    return;
  }

  constexpr int CAP = 1024;
  __shared__ unsigned e_raw[CAP];   // (dc<<26)|(j<<12)|r
  __shared__ float    v_raw[CAP];
  __shared__ uint2    ev_srt[CAP];  // .x = packed meta, .y = float bits
  __shared__ int cnt;
  __shared__ int cstart[65];
  __shared__ int coff[64];
  __shared__ int ccnt[64];
  __shared__ unsigned walsh16[16];  // walsh16[m] bit j = parity(j & m)

  const int tid = threadIdx.x;
  const int ci0 = blockIdx.x * 64;
  const int o0  = blockIdx.y * 256;

  if (tid == 0) cnt = 0;
  if (tid < 64) ccnt[tid] = 0;
  if (tid < 16) {
    unsigned m = tid;
    unsigned w = (m & 1 ? 0xAAAAu : 0u) ^ (m & 2 ? 0xCCCCu : 0u)
               ^ (m & 4 ? 0xF0F0u : 0u) ^ (m & 8 ? 0xFF00u : 0u);
    walsh16[m] = w;
  }
  __syncthreads();

  // Phase 1: collect this group's entries
  for (int j = tid; j < NFREQ; j += 256) {
    int c = idx[NFREQ + j];
    if ((c >> 6) == (int)blockIdx.x) {
      int p = atomicAdd(&cnt, 1);
      if (p < CAP) {
        e_raw[p] = ((unsigned)(c & 63) << 26) | ((unsigned)j << 12) | (unsigned)idx[j];
        v_raw[p] = spectrum[j];
        atomicAdd(&ccnt[c & 63], 1);
      }
    }
  }
  __syncthreads();
  const int n = cnt < CAP ? cnt : CAP;

  // Phase 2: prefix sum over 64 column counts (wave 0), then scatter sorted
  if (tid < 64) {
    int v = ccnt[tid];
    int s = v;
    for (int d = 1; d < 64; d <<= 1) {
      int o = __shfl_up(s, d, 64);
      if (tid >= d) s += o;
    }
    cstart[tid + 1] = s;
    if (tid == 0) cstart[0] = 0;
    coff[tid] = s - v;   // exclusive
  }
  __syncthreads();
  for (int e = tid; e < n; e += 256) {
    unsigned w = e_raw[e];
    int dc = w >> 26;
    int p = atomicAdd(&coff[dc], 1);
    ev_srt[p] = make_uint2(w, __float_as_uint(v_raw[e]));
  }
  __syncthreads();

  // Phase 3: last-wins dedup within each column bucket (LDS-local)
  for (int e = tid; e < n; e += 256) {
    uint2 ev = ev_srt[e];
    int dc = ev.x >> 26;
    unsigned r = ev.x & 0xFFFu, j = (ev.x >> 12) & 0x3FFFu;
    int s0 = cstart[dc], e0 = cstart[dc + 1];
    bool dead = false;
    for (int p = s0; p < e0; ++p) {
      unsigned w2 = ev_srt[p].x;
      if ((w2 & 0xFFFu) == r && ((w2 >> 12) & 0x3FFFu) > j) dead = true;
    }
    if (dead) ev_srt[e].y = 0u;   // +0.0f: additive no-op == excluded
  }
  __syncthreads();

  // Phase 4: thread = 4 consecutive cols x 16 CONTIGUOUS rows, entry-outer.
  const int dc0   = (tid & 15) * 4;
  const int rof   = tid >> 4;
  const int obase = o0 + rof * 16;

  float acc[4][16];
#pragma unroll
  for (int c = 0; c < 4; ++c)
#pragma unroll
    for (int j = 0; j < 16; ++j) acc[c][j] = 0.0f;

#pragma unroll
  for (int c = 0; c < 4; ++c) {
    const int s = cstart[dc0 + c], e = cstart[dc0 + c + 1];
    for (int p = s; p < e; ++p) {
      uint2 ev = ev_srt[p];                       // one ds_read_b64 per entry
      unsigned r = ev.x & 0xFFFu;
      unsigned W = walsh16[r & 15u];              // 16-row sign pattern
      unsigned sx = ev.y ^ ((unsigned)(__popc(obase & r) & 1) << 31);  // ±v base sign
#pragma unroll
      for (int j = 0; j < 16; ++j) {
        // bit j of W -> sign bit: shift into bit31, mask, xor, add  (4 VALU)
        acc[c][j] += __uint_as_float(sx ^ ((W << (31 - j)) & 0x80000000u));
      }
    }
  }

  // Epilogue: 16 rows, float4 weight load + ushort4 store (coalesced)
  size_t g = (size_t)obase * K_DIM + ci0 + dc0;
#pragma unroll 4
  for (int j = 0; j < 16; ++j) {
    float4 w4 = *(const float4*)&weight[g];
    ushort4 ov;
    ov.x = f2bf(w4.x + SCALE * acc[0][j]);
    ov.y = f2bf(w4.y + SCALE * acc[1][j]);
    ov.z = f2bf(w4.z + SCALE * acc[2][j]);
    ov.w = f2bf(w4.w + SCALE * acc[3][j]);
    *(ushort4*)&wb[g] = ov;
    g += K_DIM;
  }
}

// ---------------------------------------------------------------------------
// Kernel 2: C[M,N] = A[M,K] * B[N,K]^T  (bf16 in, fp32 out), split-K via z.
// 128x128 tile, BK=64, XOR-swizzled LDS (conflict-free ds_read_b128),
// global_load_lds(16B) staging, mfma_f32_16x16x32_bf16, 32 MFMA per barrier.
// z==0 writes C0 (out); z>0 writes C1 + (z-1)*M*N (partials).
// Block-id layout: blocks sharing bn differ by 32 in linear id -> same XCD
// (mod 8) -> B stripe stays L2-local.
// ---------------------------------------------------------------------------
__global__ __launch_bounds__(256) void gemm_bt(
    const ushort_t* __restrict__ A,   // xb [M,K]
    const ushort_t* __restrict__ B,   // wb [N,K]
    float* __restrict__ C0,
    float* __restrict__ C1,
    int klen) {
  constexpr int BM = 128, BN = 128, BK = 64;
  __shared__ __align__(16) ushort_t As[BM * BK];   // 16 KB
  __shared__ __align__(16) ushort_t Bs[BN * BK];   // 16 KB

  const int tid  = threadIdx.x;
  const int wave = tid >> 6, lane = tid & 63;
  const int wrow = wave >> 1, wcol = wave & 1;
  const int l16  = lane & 15, quad = lane >> 4;
  const int bm = blockIdx.y * BM, bn = blockIdx.x * BN;
  const int kbeg = blockIdx.z * klen;
  float* __restrict__ dst = blockIdx.z == 0
      ? C0 : C1 + (size_t)(blockIdx.z - 1) * M_DIM * N_DIM;

  const int srow8 = lane >> 3;          // row within chunk, 0..7
  const int sq    = lane & 7;           // 16B slot within row, 0..7

  f32x4_t acc[4][4] = {};

  for (int kt = kbeg; kt < kbeg + klen; kt += BK) {
#pragma unroll
    for (int c = 0; c < 4; ++c) {
      int ch = wave * 4 + c;            // wave-uniform
      int gr = ch * 8 + srow8;          // tile row 0..127
      int qg = sq ^ (gr & 7);           // swizzled source quad
      const ushort_t* ga = A + (size_t)(bm + gr) * K_DIM + kt + qg * 8;
      __builtin_amdgcn_global_load_lds(
          (const __attribute__((address_space(1))) void*)ga,
          (__attribute__((address_space(3))) void*)&As[ch * 512], 16, 0, 0);
      const ushort_t* gb = B + (size_t)(bn + gr) * K_DIM + kt + qg * 8;
      __builtin_amdgcn_global_load_lds(
          (const __attribute__((address_space(1))) void*)gb,
          (__attribute__((address_space(3))) void*)&Bs[ch * 512], 16, 0, 0);
    }
    __syncthreads();

    bf16x8_t af[2][4], bfr[2][4];
#pragma unroll
    for (int h = 0; h < 2; ++h) {
#pragma unroll
      for (int i = 0; i < 4; ++i) {
        int kq = h * 4 + quad;
        int ar = wrow * 64 + i * 16 + l16;
        af[h][i]  = *(const bf16x8_t*)&As[ar * BK + ((kq ^ (ar & 7)) * 8)];
        int br = wcol * 64 + i * 16 + l16;
        bfr[h][i] = *(const bf16x8_t*)&Bs[br * BK + ((kq ^ (br & 7)) * 8)];
      }
    }
#pragma unroll
    for (int h = 0; h < 2; ++h)
#pragma unroll
      for (int i = 0; i < 4; ++i)
#pragma unroll
        for (int j = 0; j < 4; ++j)
          acc[i][j] = __builtin_amdgcn_mfma_f32_16x16x32_bf16(af[h][i], bfr[h][j], acc[i][j], 0, 0, 0);
    __syncthreads();
  }

  // epilogue: C/D layout col = lane&15 (n side), row = quad*4 + reg (m side)
#pragma unroll
  for (int i = 0; i < 4; ++i) {
#pragma unroll
    for (int j = 0; j < 4; ++j) {
      int col = bn + wcol * 64 + j * 16 + l16;
#pragma unroll
      for (int r = 0; r < 4; ++r) {
        int row = bm + wrow * 64 + i * 16 + quad * 4 + r;
        dst[(size_t)row * N_DIM + col] = acc[i][j][r];
      }
    }
  }
}

// ---------------------------------------------------------------------------
// Kernel 3: out += sum of npart partial arrays (float4)
// ---------------------------------------------------------------------------
__global__ __launch_bounds__(256) void reduce_n(float* __restrict__ out,
                                                const float* __restrict__ part,
                                                int npart) {
  int i = blockIdx.x * 256 + threadIdx.x;
  float4 a = ((const float4*)out)[i];
  for (int t = 0; t < npart; ++t) {
    float4 b = ((const float4*)(part + (size_t)t * M_DIM * N_DIM))[i];
    a.x += b.x; a.y += b.y; a.z += b.z; a.w += b.w;
  }
  ((float4*)out)[i] = a;
}

extern "C" void kernel_launch(void* const* d_in, const int* in_sizes, int n_in,
                              void* d_out, int out_size, void* d_ws, size_t ws_size,
                              hipStream_t stream) {
  const float* x        = (const float*)d_in[0];   // [2,512,4096]
  const float* weight   = (const float*)d_in[1];   // [4096,4096]
  const float* spectrum = (const float*)d_in[2];   // [10000]
  const int*   indices  = (const int*)d_in[3];     // [2,10000]
  float* out = (float*)d_out;                      // [2,512,4096]

  char* ws = (char*)d_ws;
  const size_t WB_BYTES = (size_t)N_DIM * K_DIM * 2;   // 32 MB
  const size_t XB_BYTES = (size_t)M_DIM * K_DIM * 2;   //  8 MB
  const size_t P1_BYTES = (size_t)M_DIM * N_DIM * 4;   // 16 MB per partial

  ushort_t* wb = (ushort_t*)ws;
  ushort_t* xb = (ushort_t*)(ws + WB_BYTES);
  float* part = (float*)(ws + WB_BYTES + XB_BYTES);

  int zsplit;
  if (ws_size >= WB_BYTES + XB_BYTES + 3 * P1_BYTES)      zsplit = 4;
  else if (ws_size >= WB_BYTES + XB_BYTES + P1_BYTES)     zsplit = 2;
  else                                                    zsplit = 1;

  // build W' (y=0..15) + convert x (y=16) in one dispatch
  build_w4<<<dim3(64, 17), 256, 0, stream>>>(weight, spectrum, indices, x, wb, xb);

  gemm_bt<<<dim3(N_DIM / 128, M_DIM / 128, zsplit), 256, 0, stream>>>(
      xb, wb, out, part, K_DIM / zsplit);
  if (zsplit > 1)
    reduce_n<<<(M_DIM * N_DIM / 4) / 256, 256, 0, stream>>>(out, part, zsplit - 1);
}

// Round 5
// 200.576 us; speedup vs baseline: 1.1271x; 1.1271x over previous
//
#include <hip/hip_runtime.h>

typedef unsigned short ushort_t;

#define M_DIM 1024   // 2*512 rows of x
#define N_DIM 4096   // OUT_F
#define K_DIM 4096   // IN_F
#define NFREQ 10000
constexpr float SCALE = 150.0f / 64.0f;   // 150 / sqrt(4096)

typedef __bf16 bf16x8_t __attribute__((ext_vector_type(8)));
typedef float  f32x4_t  __attribute__((ext_vector_type(4)));

__device__ inline ushort_t f2bf(float f) {
  union { float f; unsigned u; } v; v.f = f;
  unsigned r = v.u + 0x7fffu + ((v.u >> 16) & 1u);   // RNE
  return (ushort_t)(r >> 16);
}

// ---------------------------------------------------------------------------
// Kernel 1: W' = bf16( weight + s * iwht(scatter(spectrum, indices)) ), plus
// x fp32->bf16 folded in as extra grid-y slice.
// Entry-outer evaluation: each entry read ONCE per thread, signs for 16
// contiguous rows come from a Walsh LUT bit pattern (4 VALU per entry-row).
// ALL acc indices are compile-time (full unroll) -> acc stays in VGPRs.
// ---------------------------------------------------------------------------
__global__ __launch_bounds__(256) void build_w4(
    const float* __restrict__ weight,
    const float* __restrict__ spectrum,
    const int* __restrict__ idx,          // [2][NFREQ]: row 0 = r (out), row 1 = c (in)
    const float* __restrict__ x,
    ushort_t* __restrict__ wb,
    ushort_t* __restrict__ xb) {
  // ---- folded cvt_x slice ----
  if (blockIdx.y == 16) {
    int flat = blockIdx.x * 256 + threadIdx.x;    // 16384 threads
#pragma unroll 4
    for (int k = 0; k < 64; ++k) {
      int i = flat + k * 16384;                   // M*K/4 = 1048576 float4s
      float4 v = ((const float4*)x)[i];
      ushort4 o;
      o.x = f2bf(v.x); o.y = f2bf(v.y); o.z = f2bf(v.z); o.w = f2bf(v.w);
      ((ushort4*)xb)[i] = o;
    }
    return;
  }

  constexpr int CAP = 1024;
  __shared__ unsigned e_raw[CAP];   // (dc<<26)|(j<<12)|r
  __shared__ float    v_raw[CAP];
  __shared__ uint2    ev_srt[CAP];  // .x = packed meta, .y = float bits
  __shared__ int cnt;
  __shared__ int cstart[65];
  __shared__ int coff[64];
  __shared__ int ccnt[64];
  __shared__ unsigned walsh16[16];  // walsh16[m] bit j = parity(j & m)

  const int tid = threadIdx.x;
  const int ci0 = blockIdx.x * 64;
  const int o0  = blockIdx.y * 256;

  if (tid == 0) cnt = 0;
  if (tid < 64) ccnt[tid] = 0;
  if (tid < 16) {
    unsigned m = tid;
    unsigned w = (m & 1 ? 0xAAAAu : 0u) ^ (m & 2 ? 0xCCCCu : 0u)
               ^ (m & 4 ? 0xF0F0u : 0u) ^ (m & 8 ? 0xFF00u : 0u);
    walsh16[m] = w;
  }
  __syncthreads();

  // Phase 1: collect this group's entries
  for (int j = tid; j < NFREQ; j += 256) {
    int c = idx[NFREQ + j];
    if ((c >> 6) == (int)blockIdx.x) {
      int p = atomicAdd(&cnt, 1);
      if (p < CAP) {
        e_raw[p] = ((unsigned)(c & 63) << 26) | ((unsigned)j << 12) | (unsigned)idx[j];
        v_raw[p] = spectrum[j];
        atomicAdd(&ccnt[c & 63], 1);
      }
    }
  }
  __syncthreads();
  const int n = cnt < CAP ? cnt : CAP;

  // Phase 2: prefix sum over 64 column counts (wave 0), then scatter sorted
  if (tid < 64) {
    int v = ccnt[tid];
    int s = v;
    for (int d = 1; d < 64; d <<= 1) {
      int o = __shfl_up(s, d, 64);
      if (tid >= d) s += o;
    }
    cstart[tid + 1] = s;
    if (tid == 0) cstart[0] = 0;
    coff[tid] = s - v;   // exclusive
  }
  __syncthreads();
  for (int e = tid; e < n; e += 256) {
    unsigned w = e_raw[e];
    int dc = w >> 26;
    int p = atomicAdd(&coff[dc], 1);
    ev_srt[p] = make_uint2(w, __float_as_uint(v_raw[e]));
  }
  __syncthreads();

  // Phase 3: last-wins dedup within each column bucket (LDS-local)
  for (int e = tid; e < n; e += 256) {
    uint2 ev = ev_srt[e];
    int dc = ev.x >> 26;
    unsigned r = ev.x & 0xFFFu, j = (ev.x >> 12) & 0x3FFFu;
    int s0 = cstart[dc], e0 = cstart[dc + 1];
    bool dead = false;
    for (int p = s0; p < e0; ++p) {
      unsigned w2 = ev_srt[p].x;
      if ((w2 & 0xFFFu) == r && ((w2 >> 12) & 0x3FFFu) > j) dead = true;
    }
    if (dead) ev_srt[e].y = 0u;   // +0.0f: additive no-op == excluded
  }
  __syncthreads();

  // Phase 4: thread = 4 consecutive cols x 16 CONTIGUOUS rows, entry-outer.
  const int dc0   = (tid & 15) * 4;
  const int rof   = tid >> 4;
  const int obase = o0 + rof * 16;

  float acc[4][16];
#pragma unroll
  for (int c = 0; c < 4; ++c)
#pragma unroll
    for (int j = 0; j < 16; ++j) acc[c][j] = 0.0f;

#pragma unroll
  for (int c = 0; c < 4; ++c) {
    const int s = cstart[dc0 + c], e = cstart[dc0 + c + 1];
    for (int p = s; p < e; ++p) {
      uint2 ev = ev_srt[p];                       // one ds_read_b64 per entry
      unsigned r = ev.x & 0xFFFu;
      unsigned W = walsh16[r & 15u];              // 16-row sign pattern
      unsigned sx = ev.y ^ ((unsigned)(__popc(obase & r) & 1) << 31);  // ±v base sign
#pragma unroll
      for (int j = 0; j < 16; ++j) {
        // bit j of W -> sign bit: shift into bit31, mask, xor, add  (4 VALU)
        acc[c][j] += __uint_as_float(sx ^ ((W << (31 - j)) & 0x80000000u));
      }
    }
  }

  // Epilogue: 16 rows, float4 weight load + ushort4 store (coalesced).
  // FULL unroll: every acc index must be a compile-time constant, otherwise
  // the whole acc array is demoted to scratch (R4 regression: VGPR=48,
  // WRITE_SIZE 4x inflated by spill traffic).
  size_t g = (size_t)obase * K_DIM + ci0 + dc0;
#pragma unroll
  for (int j = 0; j < 16; ++j) {
    float4 w4 = *(const float4*)&weight[g];
    ushort4 ov;
    ov.x = f2bf(w4.x + SCALE * acc[0][j]);
    ov.y = f2bf(w4.y + SCALE * acc[1][j]);
    ov.z = f2bf(w4.z + SCALE * acc[2][j]);
    ov.w = f2bf(w4.w + SCALE * acc[3][j]);
    *(ushort4*)&wb[g] = ov;
    g += K_DIM;
  }
}

// ---------------------------------------------------------------------------
// Kernel 2: C[M,N] = A[M,K] * B[N,K]^T  (bf16 in, fp32 out), split-K via z.
// 128x128 tile, BK=64, XOR-swizzled LDS (conflict-free ds_read_b128),
// global_load_lds(16B) staging, mfma_f32_16x16x32_bf16, 32 MFMA per barrier.
// z==0 writes C0 (out); z>0 writes C1 + (z-1)*M*N (partials).
// ---------------------------------------------------------------------------
__global__ __launch_bounds__(256) void gemm_bt(
    const ushort_t* __restrict__ A,   // xb [M,K]
    const ushort_t* __restrict__ B,   // wb [N,K]
    float* __restrict__ C0,
    float* __restrict__ C1,
    int klen) {
  constexpr int BM = 128, BN = 128, BK = 64;
  __shared__ __align__(16) ushort_t As[BM * BK];   // 16 KB
  __shared__ __align__(16) ushort_t Bs[BN * BK];   // 16 KB

  const int tid  = threadIdx.x;
  const int wave = tid >> 6, lane = tid & 63;
  const int wrow = wave >> 1, wcol = wave & 1;
  const int l16  = lane & 15, quad = lane >> 4;
  const int bm = blockIdx.y * BM, bn = blockIdx.x * BN;
  const int kbeg = blockIdx.z * klen;
  float* __restrict__ dst = blockIdx.z == 0
      ? C0 : C1 + (size_t)(blockIdx.z - 1) * M_DIM * N_DIM;

  const int srow8 = lane >> 3;          // row within chunk, 0..7
  const int sq    = lane & 7;           // 16B slot within row, 0..7

  f32x4_t acc[4][4] = {};

  for (int kt = kbeg; kt < kbeg + klen; kt += BK) {
#pragma unroll
    for (int c = 0; c < 4; ++c) {
      int ch = wave * 4 + c;            // wave-uniform
      int gr = ch * 8 + srow8;          // tile row 0..127
      int qg = sq ^ (gr & 7);           // swizzled source quad
      const ushort_t* ga = A + (size_t)(bm + gr) * K_DIM + kt + qg * 8;
      __builtin_amdgcn_global_load_lds(
          (const __attribute__((address_space(1))) void*)ga,
          (__attribute__((address_space(3))) void*)&As[ch * 512], 16, 0, 0);
      const ushort_t* gb = B + (size_t)(bn + gr) * K_DIM + kt + qg * 8;
      __builtin_amdgcn_global_load_lds(
          (const __attribute__((address_space(1))) void*)gb,
          (__attribute__((address_space(3))) void*)&Bs[ch * 512], 16, 0, 0);
    }
    __syncthreads();

    bf16x8_t af[2][4], bfr[2][4];
#pragma unroll
    for (int h = 0; h < 2; ++h) {
#pragma unroll
      for (int i = 0; i < 4; ++i) {
        int kq = h * 4 + quad;
        int ar = wrow * 64 + i * 16 + l16;
        af[h][i]  = *(const bf16x8_t*)&As[ar * BK + ((kq ^ (ar & 7)) * 8)];
        int br = wcol * 64 + i * 16 + l16;
        bfr[h][i] = *(const bf16x8_t*)&Bs[br * BK + ((kq ^ (br & 7)) * 8)];
      }
    }
#pragma unroll
    for (int h = 0; h < 2; ++h)
#pragma unroll
      for (int i = 0; i < 4; ++i)
#pragma unroll
        for (int j = 0; j < 4; ++j)
          acc[i][j] = __builtin_amdgcn_mfma_f32_16x16x32_bf16(af[h][i], bfr[h][j], acc[i][j], 0, 0, 0);
    __syncthreads();
  }

  // epilogue: C/D layout col = lane&15 (n side), row = quad*4 + reg (m side)
#pragma unroll
  for (int i = 0; i < 4; ++i) {
#pragma unroll
    for (int j = 0; j < 4; ++j) {
      int col = bn + wcol * 64 + j * 16 + l16;
#pragma unroll
      for (int r = 0; r < 4; ++r) {
        int row = bm + wrow * 64 + i * 16 + quad * 4 + r;
        dst[(size_t)row * N_DIM + col] = acc[i][j][r];
      }
    }
  }
}

// ---------------------------------------------------------------------------
// Kernel 3: out += sum of npart partial arrays (float4)
// ---------------------------------------------------------------------------
__global__ __launch_bounds__(256) void reduce_n(float* __restrict__ out,
                                                const float* __restrict__ part,
                                                int npart) {
  int i = blockIdx.x * 256 + threadIdx.x;
  float4 a = ((const float4*)out)[i];
  for (int t = 0; t < npart; ++t) {
    float4 b = ((const float4*)(part + (size_t)t * M_DIM * N_DIM))[i];
    a.x += b.x; a.y += b.y; a.z += b.z; a.w += b.w;
  }
  ((float4*)out)[i] = a;
}

extern "C" void kernel_launch(void* const* d_in, const int* in_sizes, int n_in,
                              void* d_out, int out_size, void* d_ws, size_t ws_size,
                              hipStream_t stream) {
  const float* x        = (const float*)d_in[0];   // [2,512,4096]
  const float* weight   = (const float*)d_in[1];   // [4096,4096]
  const float* spectrum = (const float*)d_in[2];   // [10000]
  const int*   indices  = (const int*)d_in[3];     // [2,10000]
  float* out = (float*)d_out;                      // [2,512,4096]

  char* ws = (char*)d_ws;
  const size_t WB_BYTES = (size_t)N_DIM * K_DIM * 2;   // 32 MB
  const size_t XB_BYTES = (size_t)M_DIM * K_DIM * 2;   //  8 MB
  const size_t P1_BYTES = (size_t)M_DIM * N_DIM * 4;   // 16 MB per partial

  ushort_t* wb = (ushort_t*)ws;
  ushort_t* xb = (ushort_t*)(ws + WB_BYTES);
  float* part = (float*)(ws + WB_BYTES + XB_BYTES);

  int zsplit;
  if (ws_size >= WB_BYTES + XB_BYTES + 3 * P1_BYTES)      zsplit = 4;
  else if (ws_size >= WB_BYTES + XB_BYTES + P1_BYTES)     zsplit = 2;
  else                                                    zsplit = 1;

  // build W' (y=0..15) + convert x (y=16) in one dispatch
  build_w4<<<dim3(64, 17), 256, 0, stream>>>(weight, spectrum, indices, x, wb, xb);

  gemm_bt<<<dim3(N_DIM / 128, M_DIM / 128, zsplit), 256, 0, stream>>>(
      xb, wb, out, part, K_DIM / zsplit);
  if (zsplit > 1)
    reduce_n<<<(M_DIM * N_DIM / 4) / 256, 256, 0, stream>>>(out, part, zsplit - 1);
}